// Round 11
// baseline (135.676 us; speedup 1.0000x reference)
//
#include <hip/hip_runtime.h>
#include <hip/hip_bf16.h>

typedef __bf16 bf16;
typedef __bf16 bf16x4 __attribute__((ext_vector_type(4)));
typedef __bf16 bf16x8 __attribute__((ext_vector_type(8)));
typedef float f32x4 __attribute__((ext_vector_type(4)));
typedef float f32x16 __attribute__((ext_vector_type(16)));

#define B_  32
#define C_  256
#define N_  1024
#define G_  8
#define CG_ 32
#define O3_ 768

// LDS XOR swizzles (element-index form). 8-element (16B) chunks preserved.
// 512B rows (256 bf16/row), 4-bit: slot ^= row&15
#define SWZ9(el) ((el) ^ ((((el) >> 8) & 15) << 3))
// 512B rows, 5-bit (for 32-row-phase reads): slot ^= row&31
#define SWZK(el) ((el) ^ ((((el) >> 8) & 31) << 3))
// 128B rows (64 bf16/row): slot ^= row&7
#define SWZ7(el) ((el) ^ ((((el) >> 6) & 7) << 3))

// async global->LDS, 16B per lane. LDS dest must be wave-uniform base (lanes
// auto-scatter base + lane*16); global src is per-lane.
#define GLOAD16(gp, lp)                                                        \
    __builtin_amdgcn_global_load_lds(                                          \
        (const __attribute__((address_space(1))) void*)(gp),                   \
        (__attribute__((address_space(3))) void*)(lp), 16, 0, 0)

// ---------------- kernel 0: weights f32 -> bf16 ----------------
__global__ __launch_bounds__(256) void k_convert(const float* __restrict__ qkv_w,
                                                 const float* __restrict__ out_w,
                                                 bf16* __restrict__ qkv_wh,
                                                 bf16* __restrict__ out_wh) {
    int i = blockIdx.x * 256 + threadIdx.x;
    if (i < O3_ * C_) qkv_wh[i] = (bf16)qkv_w[i];
    if (i < C_ * C_)  out_wh[i] = (bf16)out_w[i];
}

// ---------------- kernel 1: group norm (float4 vectorized) ----------------
__global__ __launch_bounds__(256) void k_gn(const float* __restrict__ x,
                                            const float* __restrict__ w,
                                            const float* __restrict__ bia,
                                            bf16* __restrict__ xn,
                                            bf16* __restrict__ xt) {
    int bg = blockIdx.x;
    int b = bg >> 3, g = bg & 7;
    const float4* xb4 = (const float4*)(x + (size_t)b * C_ * N_ + (size_t)g * CG_ * N_);
    int tid = threadIdx.x;

    float s = 0.f, ss = 0.f;
    for (int i = tid; i < CG_ * N_ / 4; i += 256) {
        float4 v = xb4[i];
        s  += v.x + v.y + v.z + v.w;
        ss += v.x * v.x + v.y * v.y + v.z * v.z + v.w * v.w;
    }
    for (int off = 32; off; off >>= 1) {
        s  += __shfl_down(s, off);
        ss += __shfl_down(ss, off);
    }
    __shared__ float red[8];
    __shared__ float stat[2];
    int wid = tid >> 6, lane = tid & 63;
    if (lane == 0) { red[wid] = s; red[wid + 4] = ss; }
    __syncthreads();
    if (tid == 0) {
        float S  = red[0] + red[1] + red[2] + red[3];
        float SS = red[4] + red[5] + red[6] + red[7];
        float mu = S / (float)(CG_ * N_);
        float var = SS / (float)(CG_ * N_) - mu * mu;
        stat[0] = mu;
        stat[1] = rsqrtf(var + 1e-5f);
    }
    __syncthreads();
    float mu = stat[0], rstd = stat[1];

    __shared__ bf16 tile[256][CG_ + 8];
    for (int nc = 0; nc < N_; nc += 256) {
        for (int i = tid; i < 2048; i += 256) {
            int cl = i >> 6, f = i & 63;
            int c = g * CG_ + cl;
            float sc = rstd * w[c], sh = bia[c] - mu * sc;
            float4 v = xb4[(size_t)cl * 256 + (nc >> 2) + f];
            bf16x4 h = { (bf16)(v.x * sc + sh), (bf16)(v.y * sc + sh),
                         (bf16)(v.z * sc + sh), (bf16)(v.w * sc + sh) };
            *(bf16x4*)(xn + (size_t)b * C_ * N_ + (size_t)c * N_ + nc + f * 4) = h;
            tile[f * 4 + 0][cl] = h[0];
            tile[f * 4 + 1][cl] = h[1];
            tile[f * 4 + 2][cl] = h[2];
            tile[f * 4 + 3][cl] = h[3];
        }
        __syncthreads();
        for (int u = tid; u < 256 * 4; u += 256) {
            int nl = u >> 2, ch = u & 3;
            bf16x8 v = *(const bf16x8*)&tile[nl][ch * 8];
            *(bf16x8*)(xt + (size_t)b * N_ * C_ + (size_t)(nc + nl) * C_ + g * CG_ + ch * 8) = v;
        }
        __syncthreads();
    }
}

// ---------------- kernel 2: QKV GEMM ----------------
// Q outputs (ot<2) are pre-scaled by 1/sqrt(C)=1/16 (exact pow2, bit-exact).
__global__ __launch_bounds__(256) void k_qkv(const bf16* __restrict__ xt,
                                             const bf16* __restrict__ wq,
                                             const float* __restrict__ qb,
                                             bf16* __restrict__ Qs,
                                             bf16* __restrict__ Kt,
                                             bf16* __restrict__ Vt) {
    __shared__ bf16 smem[17408];
    bf16* aT = smem;                      // [128][64], swizzled
    bf16* bT = smem + 8192;               // [128][64], swizzled
    int nt = blockIdx.x, ot = blockIdx.y, b = blockIdx.z;
    int tid = threadIdx.x, wid = tid >> 6, lane = tid & 63;
    int wr = wid >> 1, wc = wid & 1;
    const bf16* Ab = xt + (size_t)b * N_ * C_ + (size_t)nt * 128 * C_;
    const bf16* Bb = wq + (size_t)ot * 128 * C_;

    bf16x8 areg[4], breg[4];
    #define LOAD_KT(kt)                                                        \
        for (int j = 0; j < 4; ++j) {                                          \
            int lin = (j * 256 + tid) * 8;                                     \
            int row = lin >> 6, col = lin & 63;                                \
            areg[j] = *(const bf16x8*)&Ab[(size_t)row * C_ + (kt) * 64 + col]; \
            breg[j] = *(const bf16x8*)&Bb[(size_t)row * C_ + (kt) * 64 + col]; \
        }

    f32x4 acc[4][4] = {};
    LOAD_KT(0);
    for (int kt = 0; kt < 4; ++kt) {
        for (int j = 0; j < 4; ++j) {
            int lin = (j * 256 + tid) * 8;
            *(bf16x8*)&aT[SWZ7(lin)] = areg[j];
            *(bf16x8*)&bT[SWZ7(lin)] = breg[j];
        }
        __syncthreads();
        if (kt < 3) { LOAD_KT(kt + 1); }
        for (int kk = 0; kk < 2; ++kk) {
            bf16x8 af[4], bfr[4];
            for (int m = 0; m < 4; ++m) {
                int el = (wr * 64 + m * 16 + (lane & 15)) * 64 + kk * 32 + (lane >> 4) * 8;
                af[m] = *(const bf16x8*)&aT[SWZ7(el)];
            }
            for (int n = 0; n < 4; ++n) {
                int el = (wc * 64 + n * 16 + (lane & 15)) * 64 + kk * 32 + (lane >> 4) * 8;
                bfr[n] = *(const bf16x8*)&bT[SWZ7(el)];
            }
            for (int m = 0; m < 4; ++m)
                for (int n = 0; n < 4; ++n)
                    acc[m][n] = __builtin_amdgcn_mfma_f32_16x16x32_bf16(af[m], bfr[n], acc[m][n], 0, 0, 0);
        }
        __syncthreads();
    }
    #undef LOAD_KT

    int o0 = ot * 128;
    if (ot < 4) {
        bf16* dst = (ot < 2) ? (Qs + (size_t)b * N_ * C_) : (Kt + (size_t)b * N_ * C_);
        float qsc = (ot < 2) ? 0.0625f : 1.0f;
        for (int m = 0; m < 4; ++m) for (int n = 0; n < 4; ++n) {
            int o = o0 + wc * 64 + n * 16 + (lane & 15);
            float bias = qb[o];
            int row0 = nt * 128 + wr * 64 + m * 16 + (lane >> 4) * 4;
            for (int r = 0; r < 4; ++r)
                dst[(size_t)(row0 + r) * C_ + (o & 255)] = (bf16)((acc[m][n][r] + bias) * qsc);
        }
    } else {
        bf16* tileE = smem;               // [128][136]
        for (int m = 0; m < 4; ++m) for (int n = 0; n < 4; ++n) {
            int ol = wc * 64 + n * 16 + (lane & 15);
            float bias = qb[o0 + ol];
            int rl0 = wr * 64 + m * 16 + (lane >> 4) * 4;
            for (int r = 0; r < 4; ++r)
                tileE[(size_t)ol * 136 + rl0 + r] = (bf16)(acc[m][n][r] + bias);
        }
        __syncthreads();
        bf16* Vb = Vt + (size_t)b * C_ * N_ + (size_t)(o0 - 512) * N_ + (size_t)nt * 128;
        for (int u = tid; u < 128 * 16; u += 256) {
            int ol = u >> 4, ch = u & 15;
            bf16x8 v = *(const bf16x8*)&tileE[ol * 136 + ch * 8];
            *(bf16x8*)&Vb[(size_t)ol * N_ + ch * 8] = v;
        }
    }
}

// ---------------- kernel 3: fused attention (v10: 32x32 QK, KVBLK=64) ----------------
// 64 q-rows/block; 4 waves = (2 q-halves x 2 kv-halves). Each wave computes one
// 32x32 S-quadrant via mfma_f32_32x32x16_bf16 (A=Q regs, B=K-tile slice): per
// wave only HALF the K tile is read, and 32 q-rows share it -> QK LDS reads
// drop 4x vs R9. PV unchanged (16x16, channel-split 4 ways). No-max softmax,
// per-lane deferred sums (combined across kv-half waves at epilogue via LDS).
// K[64][256] SWZK (5-bit row swizzle, conflict-free for 32-row phases);
// V[256][64] SWZ7. Dbuf via global_load_lds; LDS 137.5KB -> 1 block/CU.
// Grid (32 batch, 16 qb) batch-fastest -> K/V L2-local per XCD.
__global__ __launch_bounds__(256, 1) void k_attn(const bf16* __restrict__ Qs,
                                                 const bf16* __restrict__ Kt,
                                                 const bf16* __restrict__ Vt,
                                                 bf16* __restrict__ Ao) {
    extern __shared__ char smem[];
    bf16*  kbuf = (bf16*)smem;                  // 2 x 16384 el (64KB)
    bf16*  vbuf = (bf16*)(smem + 65536);        // 2 x 16384 el (64KB)
    bf16*  pl   = (bf16*)(smem + 131072);       // 64 x 72 el = 9216 B
    float* al   = (float*)(smem + 140288);      // 128 floats (2 kv-half sums)
    int b = blockIdx.x, qb = blockIdx.y;
    int tid = threadIdx.x, wid = tid >> 6, lane = tid & 63;
    int qh = wid >> 1, kvh = wid & 1;
    int l31 = lane & 31, hi = lane >> 5;
    const bf16* Qb = Qs + (size_t)b * N_ * C_;
    const bf16* Kb = Kt + (size_t)b * N_ * C_;
    const bf16* Vb = Vt + (size_t)b * C_ * N_;
    int q0 = qb * 64;

    // Q fragments for 32x32x16: row = q0+qh*32+l31, k = kt*16 + hi*8 (+0..7)
    bf16x8 qf[16];
    {
        const bf16* qr = Qb + (size_t)(q0 + qh * 32 + l31) * C_ + hi * 8;
        #pragma unroll
        for (int kt = 0; kt < 16; ++kt) qf[kt] = *(const bf16x8*)(qr + kt * 16);
    }

    f32x4 oac[4][4] = {};      // O[64q x 64ch]: row m*16+(lane>>4)*4+r, ch wid*64+n*16+(lane&15)
    float lrun[16];
    #pragma unroll
    for (int i = 0; i < 16; ++i) lrun[i] = 0.f;

    auto stage = [&](int mt, int bi) {
        int m0 = mt * 64;
        bf16* kd = kbuf + bi * 16384;
        bf16* vd = vbuf + bi * 16384;
        #pragma unroll
        for (int j = 0; j < 8; ++j) {
            int chunk = wid * 8 + j;                 // 0..31, wave-uniform
            int d = chunk * 512 + lane * 8;          // linear dest element
            int ek = SWZK(d);                        // involution
            int krow = ek >> 8, kcol = ek & 255;
            GLOAD16(Kb + (size_t)(m0 + krow) * C_ + kcol, kd + chunk * 512);
            int ev = SWZ7(d);
            int ch = ev >> 6, kv = ev & 63;
            GLOAD16(Vb + (size_t)ch * N_ + m0 + kv, vd + chunk * 512);
        }
    };

    stage(0, 0);
    __syncthreads();

    for (int mt = 0; mt < 16; ++mt) {
        int cur = mt & 1;
        if (mt < 15) stage(mt + 1, cur ^ 1);

        const bf16* kc = kbuf + cur * 16384;
        const bf16* vc = vbuf + cur * 16384;

        // QK^T quadrant: S[32q x 32kv] = Q(qh) . K(kvh)^T  (Q pre-scaled 1/16)
        f32x16 sac = {};
        __builtin_amdgcn_s_setprio(1);
        #pragma unroll
        for (int kt = 0; kt < 16; ++kt) {
            int el = (kvh * 32 + l31) * 256 + kt * 16 + hi * 8;
            bf16x8 kf = *(const bf16x8*)&kc[SWZK(el)];
            sac = __builtin_amdgcn_mfma_f32_32x32x16_bf16(qf[kt], kf, sac, 0, 0, 0);
        }
        __builtin_amdgcn_s_setprio(0);

        // exp (no max subtraction; clamp = overflow guard), accumulate per-lane sums
        // S layout: col(kv) = l31, row(q, local) = (i&3)+8*(i>>2)+4*hi
        {
            int pcol = kvh * 32 + l31;
            #pragma unroll
            for (int i = 0; i < 16; ++i) {
                int prow = qh * 32 + (i & 3) + 8 * (i >> 2) + 4 * hi;
                float e = __expf(fminf(sac[i], 60.f));
                lrun[i] += e;
                pl[prow * 72 + pcol] = (bf16)e;
            }
        }
        __syncthreads();   // P visible block-wide; all QK reads of kc done

        // PV channel-split: O[64q x 64ch] += P[64q x 64kv] * V[64kv x 64ch]
        __builtin_amdgcn_s_setprio(1);
        #pragma unroll
        for (int ks = 0; ks < 2; ++ks) {
            bf16x8 paf[4];
            #pragma unroll
            for (int m = 0; m < 4; ++m)
                paf[m] = *(const bf16x8*)&pl[(m * 16 + (lane & 15)) * 72 + ks * 32 + (lane >> 4) * 8];
            #pragma unroll
            for (int n = 0; n < 4; ++n) {
                int ch = wid * 64 + n * 16 + (lane & 15);
                int e = ch * 64 + ks * 32 + (lane >> 4) * 8;
                bf16x8 vf = *(const bf16x8*)&vc[SWZ7(e)];
                #pragma unroll
                for (int m = 0; m < 4; ++m)
                    oac[m][n] = __builtin_amdgcn_mfma_f32_16x16x32_bf16(paf[m], vf, oac[m][n], 0, 0, 0);
            }
        }
        __builtin_amdgcn_s_setprio(0);

        __syncthreads();   // PV reads of vc/pl done; drains t+1 loads
    }

    // epilogue: reduce per-lane partials over the 32 kv lanes (within hi-group),
    // publish per-(kv-half) row sums, combine across the two kv-half waves.
    #pragma unroll
    for (int i = 0; i < 16; ++i) {
        float s = lrun[i];
        s += __shfl_xor(s, 1);
        s += __shfl_xor(s, 2);
        s += __shfl_xor(s, 4);
        s += __shfl_xor(s, 8);
        s += __shfl_xor(s, 16);
        lrun[i] = s;
    }
    if (l31 == 0) {
        #pragma unroll
        for (int i = 0; i < 16; ++i) {
            int qrl = qh * 32 + (i & 3) + 8 * (i >> 2) + 4 * hi;
            al[kvh * 64 + qrl] = lrun[i];
        }
    }
    __syncthreads();

    #pragma unroll
    for (int m = 0; m < 4; ++m)
        #pragma unroll
        for (int r = 0; r < 4; ++r) {
            int qrl = m * 16 + (lane >> 4) * 4 + r;
            float iv = 1.f / (al[qrl] + al[64 + qrl]);
            int row = q0 + qrl;
            #pragma unroll
            for (int n = 0; n < 4; ++n)
                Ao[(size_t)b * N_ * C_ + (size_t)row * C_ + wid * 64 + n * 16 + (lane & 15)] =
                    (bf16)(oac[m][n][r] * iv);
        }
}

// ---------------- kernel 4: out proj + bias + residual ----------------
__global__ __launch_bounds__(256) void k_proj(const bf16* __restrict__ Ao,
                                              const bf16* __restrict__ wo,
                                              const float* __restrict__ ob,
                                              const bf16* __restrict__ xn,
                                              float* __restrict__ out) {
    __shared__ bf16 aT[128 * 64];
    __shared__ bf16 bT[128 * 64];
    int nt = blockIdx.x, ot = blockIdx.y, b = blockIdx.z;
    int tid = threadIdx.x, wid = tid >> 6, lane = tid & 63;
    int wr = wid >> 1, wc = wid & 1;
    const bf16* Abase = wo + (size_t)ot * 128 * C_;
    const bf16* Bbase = Ao + (size_t)b * N_ * C_ + (size_t)nt * 128 * C_;

    bf16x8 areg[4], breg[4];
    #define LOAD_KT(kt)                                                            \
        for (int j = 0; j < 4; ++j) {                                              \
            int lin = (j * 256 + tid) * 8;                                         \
            int row = lin >> 6, col = lin & 63;                                    \
            areg[j] = *(const bf16x8*)&Abase[(size_t)row * C_ + (kt) * 64 + col];  \
            breg[j] = *(const bf16x8*)&Bbase[(size_t)row * C_ + (kt) * 64 + col];  \
        }

    f32x4 acc[4][4] = {};
    LOAD_KT(0);
    for (int kt = 0; kt < 4; ++kt) {
        for (int j = 0; j < 4; ++j) {
            int lin = (j * 256 + tid) * 8;
            *(bf16x8*)&aT[SWZ7(lin)] = areg[j];
            *(bf16x8*)&bT[SWZ7(lin)] = breg[j];
        }
        __syncthreads();
        if (kt < 3) { LOAD_KT(kt + 1); }
        for (int kk = 0; kk < 2; ++kk) {
            bf16x8 af[4], bfr[4];
            for (int m = 0; m < 4; ++m) {
                int el = (wr * 64 + m * 16 + (lane & 15)) * 64 + kk * 32 + (lane >> 4) * 8;
                af[m] = *(const bf16x8*)&aT[SWZ7(el)];
            }
            for (int n = 0; n < 4; ++n) {
                int el = (wc * 64 + n * 16 + (lane & 15)) * 64 + kk * 32 + (lane >> 4) * 8;
                bfr[n] = *(const bf16x8*)&bT[SWZ7(el)];
            }
            for (int m = 0; m < 4; ++m)
                for (int n = 0; n < 4; ++n)
                    acc[m][n] = __builtin_amdgcn_mfma_f32_16x16x32_bf16(af[m], bfr[n], acc[m][n], 0, 0, 0);
        }
        __syncthreads();
    }
    #undef LOAD_KT

    for (int m = 0; m < 4; ++m) {
        int o0 = ot * 128 + wr * 64 + m * 16 + (lane >> 4) * 4;
        for (int n = 0; n < 4; ++n) {
            int col = nt * 128 + wc * 64 + n * 16 + (lane & 15);
            for (int r = 0; r < 4; ++r) {
                int o = o0 + r;
                float v = acc[m][n][r] + ob[o] + (float)xn[(size_t)b * C_ * N_ + (size_t)o * N_ + col];
                out[(size_t)b * C_ * N_ + (size_t)o * N_ + col] = v;
            }
        }
    }
}

// ---------------- launch ----------------
extern "C" void kernel_launch(void* const* d_in, const int* in_sizes, int n_in,
                              void* d_out, int out_size, void* d_ws, size_t ws_size,
                              hipStream_t stream) {
    const float* x     = (const float*)d_in[0];
    const float* gn_w  = (const float*)d_in[1];
    const float* gn_b  = (const float*)d_in[2];
    const float* qkv_w = (const float*)d_in[3];
    const float* qkv_b = (const float*)d_in[4];
    const float* out_w = (const float*)d_in[5];
    const float* out_b = (const float*)d_in[6];
    float* out = (float*)d_out;

    char* ws = (char*)d_ws;
    size_t tensor = (size_t)B_ * C_ * N_ * 2;   // 16.78 MB
    bf16* xn  = (bf16*)(ws);
    bf16* xt  = (bf16*)(ws + tensor);
    bf16* Qs  = (bf16*)(ws + 2 * tensor);
    bf16* Kt  = (bf16*)(ws + 3 * tensor);
    bf16* Vt  = (bf16*)(ws + 4 * tensor);
    bf16* Ao  = xt;                              // alias: xt dead after k_qkv
    bf16* qkv_wh = (bf16*)(ws + 5 * tensor);
    bf16* out_wh = (bf16*)(ws + 5 * tensor + (size_t)O3_ * C_ * 2);

    (void)hipFuncSetAttribute(reinterpret_cast<const void*>(&k_attn),
                              hipFuncAttributeMaxDynamicSharedMemorySize, 140800);

    k_convert<<<768, 256, 0, stream>>>(qkv_w, out_w, qkv_wh, out_wh);
    k_gn<<<256, 256, 0, stream>>>(x, gn_w, gn_b, xn, xt);
    k_qkv<<<dim3(8, 6, 32), 256, 0, stream>>>(xt, qkv_wh, qkv_b, Qs, Kt, Vt);
    k_attn<<<dim3(32, 16), 256, 140800, stream>>>(Qs, Kt, Vt, Ao);
    k_proj<<<dim3(8, 2, 32), 256, 0, stream>>>(Ao, out_wh, out_b, xn, out);
}

// Round 12
// 117.407 us; speedup vs baseline: 1.1556x; 1.1556x over previous
//
#include <hip/hip_runtime.h>
#include <hip/hip_bf16.h>

typedef __bf16 bf16;
typedef __bf16 bf16x4 __attribute__((ext_vector_type(4)));
typedef __bf16 bf16x8 __attribute__((ext_vector_type(8)));
typedef float f32x4 __attribute__((ext_vector_type(4)));

#define B_  32
#define C_  256
#define N_  1024
#define G_  8
#define CG_ 32
#define O3_ 768

// LDS XOR swizzles (element-index form). 8-element (16B) chunks preserved.
// 512B rows (256 bf16/row): slot(5b) ^= row&15
#define SWZ9(el) ((el) ^ ((((el) >> 8) & 15) << 3))
// 128B rows (64 bf16/row): slot(3b) ^= row&7
#define SWZ7(el) ((el) ^ ((((el) >> 6) & 7) << 3))

// async global->LDS, 16B per lane. LDS dest must be wave-uniform base (lanes
// auto-scatter base + lane*16); global src is per-lane.
#define GLOAD16(gp, lp)                                                        \
    __builtin_amdgcn_global_load_lds(                                          \
        (const __attribute__((address_space(1))) void*)(gp),                   \
        (__attribute__((address_space(3))) void*)(lp), 16, 0, 0)

// ---------------- kernel 1: group norm (LDS-staged single-pass) + weight convert ----------------
// Blocks 0..255: one per (b,g). Pass 1 streams the 128KB f32 slice global->LDS
// while accumulating sum/sumsq (x is read from HBM exactly ONCE). Pass 2
// normalizes from LDS (no second global read), writes xn + transposed xt.
// Blocks 256..1023: f32->bf16 weight conversion (folded launch).
__global__ __launch_bounds__(256) void k_gnconv(const float* __restrict__ x,
                                                const float* __restrict__ w,
                                                const float* __restrict__ bia,
                                                bf16* __restrict__ xn,
                                                bf16* __restrict__ xt,
                                                const float* __restrict__ qkv_w,
                                                const float* __restrict__ out_w,
                                                bf16* __restrict__ qkv_wh,
                                                bf16* __restrict__ out_wh) {
    int blk = blockIdx.x;
    int tid = threadIdx.x;
    if (blk >= 256) {
        int i = (blk - 256) * 256 + tid;
        if (i < O3_ * C_) qkv_wh[i] = (bf16)qkv_w[i];
        if (i < C_ * C_)  out_wh[i] = (bf16)out_w[i];
        return;
    }

    extern __shared__ char smem[];
    float* xs   = (float*)smem;                 // 32768 f32 = 128KB
    float4* xs4 = (float4*)smem;
    bf16* tile  = (bf16*)(smem + 131072);       // [256][40] bf16 = 20KB
    int b = blk >> 3, g = blk & 7;
    const float4* xb4 = (const float4*)(x + (size_t)b * C_ * N_ + (size_t)g * CG_ * N_);

    float s = 0.f, ss = 0.f;
    for (int i = tid; i < CG_ * N_ / 4; i += 256) {
        float4 v = xb4[i];
        xs4[i] = v;
        s  += v.x + v.y + v.z + v.w;
        ss += v.x * v.x + v.y * v.y + v.z * v.z + v.w * v.w;
    }
    for (int off = 32; off; off >>= 1) {
        s  += __shfl_down(s, off);
        ss += __shfl_down(ss, off);
    }
    __shared__ float red[8];
    __shared__ float stat[2];
    int wid = tid >> 6, lane = tid & 63;
    if (lane == 0) { red[wid] = s; red[wid + 4] = ss; }
    __syncthreads();
    if (tid == 0) {
        float S  = red[0] + red[1] + red[2] + red[3];
        float SS = red[4] + red[5] + red[6] + red[7];
        float mu = S / (float)(CG_ * N_);
        float var = SS / (float)(CG_ * N_) - mu * mu;
        stat[0] = mu;
        stat[1] = rsqrtf(var + 1e-5f);
    }
    __syncthreads();
    float mu = stat[0], rstd = stat[1];

    for (int nc = 0; nc < N_; nc += 256) {
        for (int i = tid; i < 2048; i += 256) {
            int cl = i >> 6, f = i & 63;
            int c = g * CG_ + cl;
            float sc = rstd * w[c], sh = bia[c] - mu * sc;
            float4 v = xs4[cl * 256 + (nc >> 2) + f];
            bf16x4 h = { (bf16)(v.x * sc + sh), (bf16)(v.y * sc + sh),
                         (bf16)(v.z * sc + sh), (bf16)(v.w * sc + sh) };
            *(bf16x4*)(xn + (size_t)b * C_ * N_ + (size_t)c * N_ + nc + f * 4) = h;
            tile[(f * 4 + 0) * 40 + cl] = h[0];
            tile[(f * 4 + 1) * 40 + cl] = h[1];
            tile[(f * 4 + 2) * 40 + cl] = h[2];
            tile[(f * 4 + 3) * 40 + cl] = h[3];
        }
        __syncthreads();
        for (int u = tid; u < 256 * 4; u += 256) {
            int nl = u >> 2, ch = u & 3;
            bf16x8 v = *(const bf16x8*)&tile[nl * 40 + ch * 8];
            *(bf16x8*)(xt + (size_t)b * N_ * C_ + (size_t)(nc + nl) * C_ + g * CG_ + ch * 8) = v;
        }
        __syncthreads();
    }
}

// ---------------- kernel 2: QKV GEMM ----------------
// Q outputs (ot<2) are pre-scaled by 1/sqrt(C)=1/16 (exact pow2, bit-exact).
__global__ __launch_bounds__(256) void k_qkv(const bf16* __restrict__ xt,
                                             const bf16* __restrict__ wq,
                                             const float* __restrict__ qb,
                                             bf16* __restrict__ Qs,
                                             bf16* __restrict__ Kt,
                                             bf16* __restrict__ Vt) {
    __shared__ bf16 smem[17408];
    bf16* aT = smem;                      // [128][64], swizzled
    bf16* bT = smem + 8192;               // [128][64], swizzled
    int nt = blockIdx.x, ot = blockIdx.y, b = blockIdx.z;
    int tid = threadIdx.x, wid = tid >> 6, lane = tid & 63;
    int wr = wid >> 1, wc = wid & 1;
    const bf16* Ab = xt + (size_t)b * N_ * C_ + (size_t)nt * 128 * C_;
    const bf16* Bb = wq + (size_t)ot * 128 * C_;

    bf16x8 areg[4], breg[4];
    #define LOAD_KT(kt)                                                        \
        for (int j = 0; j < 4; ++j) {                                          \
            int lin = (j * 256 + tid) * 8;                                     \
            int row = lin >> 6, col = lin & 63;                                \
            areg[j] = *(const bf16x8*)&Ab[(size_t)row * C_ + (kt) * 64 + col]; \
            breg[j] = *(const bf16x8*)&Bb[(size_t)row * C_ + (kt) * 64 + col]; \
        }

    f32x4 acc[4][4] = {};
    LOAD_KT(0);
    for (int kt = 0; kt < 4; ++kt) {
        for (int j = 0; j < 4; ++j) {
            int lin = (j * 256 + tid) * 8;
            *(bf16x8*)&aT[SWZ7(lin)] = areg[j];
            *(bf16x8*)&bT[SWZ7(lin)] = breg[j];
        }
        __syncthreads();
        if (kt < 3) { LOAD_KT(kt + 1); }
        for (int kk = 0; kk < 2; ++kk) {
            bf16x8 af[4], bfr[4];
            for (int m = 0; m < 4; ++m) {
                int el = (wr * 64 + m * 16 + (lane & 15)) * 64 + kk * 32 + (lane >> 4) * 8;
                af[m] = *(const bf16x8*)&aT[SWZ7(el)];
            }
            for (int n = 0; n < 4; ++n) {
                int el = (wc * 64 + n * 16 + (lane & 15)) * 64 + kk * 32 + (lane >> 4) * 8;
                bfr[n] = *(const bf16x8*)&bT[SWZ7(el)];
            }
            for (int m = 0; m < 4; ++m)
                for (int n = 0; n < 4; ++n)
                    acc[m][n] = __builtin_amdgcn_mfma_f32_16x16x32_bf16(af[m], bfr[n], acc[m][n], 0, 0, 0);
        }
        __syncthreads();
    }
    #undef LOAD_KT

    int o0 = ot * 128;
    if (ot < 4) {
        bf16* dst = (ot < 2) ? (Qs + (size_t)b * N_ * C_) : (Kt + (size_t)b * N_ * C_);
        float qsc = (ot < 2) ? 0.0625f : 1.0f;
        for (int m = 0; m < 4; ++m) for (int n = 0; n < 4; ++n) {
            int o = o0 + wc * 64 + n * 16 + (lane & 15);
            float bias = qb[o];
            int row0 = nt * 128 + wr * 64 + m * 16 + (lane >> 4) * 4;
            for (int r = 0; r < 4; ++r)
                dst[(size_t)(row0 + r) * C_ + (o & 255)] = (bf16)((acc[m][n][r] + bias) * qsc);
        }
    } else {
        bf16* tileE = smem;               // [128][136]
        for (int m = 0; m < 4; ++m) for (int n = 0; n < 4; ++n) {
            int ol = wc * 64 + n * 16 + (lane & 15);
            float bias = qb[o0 + ol];
            int rl0 = wr * 64 + m * 16 + (lane >> 4) * 4;
            for (int r = 0; r < 4; ++r)
                tileE[(size_t)ol * 136 + rl0 + r] = (bf16)(acc[m][n][r] + bias);
        }
        __syncthreads();
        bf16* Vb = Vt + (size_t)b * C_ * N_ + (size_t)(o0 - 512) * N_ + (size_t)nt * 128;
        for (int u = tid; u < 128 * 16; u += 256) {
            int ol = u >> 4, ch = u & 15;
            bf16x8 v = *(const bf16x8*)&tileE[ol * 136 + ch * 8];
            *(bf16x8*)&Vb[(size_t)ol * N_ + ch * 8] = v;
        }
    }
}

// ---------------- kernel 3: fused attention (v9, reverted — best known 57.8us) ----------------
// No-max softmax (scores ~N(0,1), clamp 60 overflow guard), per-lane deferred
// row sums (single epilogue reduce). 4 waves x 16 q-rows, KVBLK=32, channel-
// split PV, 2 blocks/CU, batch-fastest grid (K/V L2-local per XCD).
__global__ __launch_bounds__(256, 2) void k_attn(const bf16* __restrict__ Qs,
                                                 const bf16* __restrict__ Kt,
                                                 const bf16* __restrict__ Vt,
                                                 bf16* __restrict__ Ao) {
    extern __shared__ char smem[];
    bf16*  kbuf = (bf16*)smem;                  // 2 x 8192 el (32KB)
    bf16*  vbuf = (bf16*)(smem + 32768);        // 2 x 8192 el (32KB)
    bf16*  pl   = (bf16*)(smem + 65536);        // 64 x 40 el = 5120 B
    float* al   = (float*)(smem + 70656);       // 64 floats (1/l, epilogue)
    int b = blockIdx.x, qb = blockIdx.y;
    int tid = threadIdx.x, wid = tid >> 6, lane = tid & 63;
    const bf16* Qb = Qs + (size_t)b * N_ * C_;
    const bf16* Kb = Kt + (size_t)b * N_ * C_;
    const bf16* Vb = Vt + (size_t)b * C_ * N_;
    int q0 = qb * 64;

    bf16x8 qf[8];
    {
        int row = q0 + wid * 16 + (lane & 15);
        const bf16* qr = Qb + (size_t)row * C_ + (lane >> 4) * 8;
        #pragma unroll
        for (int kk = 0; kk < 8; ++kk) qf[kk] = *(const bf16x8*)(qr + kk * 32);
    }

    f32x4 oac[4][4] = {};      // O[64q x 64ch]: row m*16+(lane>>4)*4+r, ch wid*64+n*16+(lane&15)
    float lrun[4] = {0.f, 0.f, 0.f, 0.f};   // per-lane partial row sums

    auto stage = [&](int mt, int bi) {
        int m0 = mt * 32;
        bf16* kd = kbuf + bi * 8192;
        bf16* vd = vbuf + bi * 8192;
        #pragma unroll
        for (int j = 0; j < 4; ++j) {
            int chunk = wid * 4 + j;
            int d = chunk * 512 + lane * 8;
            int ek = SWZ9(d);
            int krow = ek >> 8, kcol = ek & 255;
            GLOAD16(Kb + (size_t)(m0 + krow) * C_ + kcol, kd + chunk * 512);
            int ev = SWZ7(d);
            int kv = ev & 31;
            int ch = ((ev >> 6) << 1) | ((ev >> 5) & 1);
            GLOAD16(Vb + (size_t)ch * N_ + m0 + kv, vd + chunk * 512);
        }
    };

    stage(0, 0);
    __syncthreads();

    for (int mt = 0; mt < 32; ++mt) {
        int cur = mt & 1;
        if (mt < 31) stage(mt + 1, cur ^ 1);

        const bf16* kc = kbuf + cur * 8192;
        const bf16* vc = vbuf + cur * 8192;

        // QK^T: S[16q x 32kv]  (Q pre-scaled by 1/16)
        f32x4 sac[2] = {};
        __builtin_amdgcn_s_setprio(1);
        #pragma unroll
        for (int kk = 0; kk < 8; ++kk)
            #pragma unroll
            for (int n = 0; n < 2; ++n) {
                int el = (n * 16 + (lane & 15)) * 256 + kk * 32 + (lane >> 4) * 8;
                bf16x8 bfr = *(const bf16x8*)&kc[SWZ9(el)];
                sac[n] = __builtin_amdgcn_mfma_f32_16x16x32_bf16(qf[kk], bfr, sac[n], 0, 0, 0);
            }
        __builtin_amdgcn_s_setprio(0);

        // exp (no max subtraction; clamp is overflow guard only)
        #pragma unroll
        for (int r = 0; r < 4; ++r) {
            int prow = (wid * 16 + (lane >> 4) * 4 + r) * 40 + (lane & 15);
            float e0 = __expf(fminf(sac[0][r], 60.f));
            float e1 = __expf(fminf(sac[1][r], 60.f));
            lrun[r] += e0 + e1;
            pl[prow]      = (bf16)e0;
            pl[prow + 16] = (bf16)e1;
        }
        __syncthreads();   // P visible block-wide

        // PV channel-split: O[64q x 64ch] += P[64q x 32kv] * V[32kv x 64ch]
        __builtin_amdgcn_s_setprio(1);
        bf16x8 paf[4];
        #pragma unroll
        for (int m = 0; m < 4; ++m)
            paf[m] = *(const bf16x8*)&pl[(m * 16 + (lane & 15)) * 40 + (lane >> 4) * 8];
        #pragma unroll
        for (int n = 0; n < 4; ++n) {
            int ch = wid * 64 + n * 16 + (lane & 15);
            int e = (ch >> 1) * 64 + (ch & 1) * 32 + (lane >> 4) * 8;
            bf16x8 bfr = *(const bf16x8*)&vc[SWZ7(e)];
            #pragma unroll
            for (int m = 0; m < 4; ++m)
                oac[m][n] = __builtin_amdgcn_mfma_f32_16x16x32_bf16(paf[m], bfr, oac[m][n], 0, 0, 0);
        }
        __builtin_amdgcn_s_setprio(0);

        __syncthreads();   // PV reads done; drains t+1 loads; frees P buffer
    }

    // epilogue: reduce per-lane partial sums across the 16 lanes of each row
    #pragma unroll
    for (int r = 0; r < 4; ++r) {
        float s = lrun[r];
        s += __shfl_xor(s, 1);
        s += __shfl_xor(s, 2);
        s += __shfl_xor(s, 4);
        s += __shfl_xor(s, 8);
        lrun[r] = s;
    }
    if (!(lane & 15)) {
        #pragma unroll
        for (int r = 0; r < 4; ++r)
            al[wid * 16 + (lane >> 4) * 4 + r] = 1.f / lrun[r];
    }
    __syncthreads();

    #pragma unroll
    for (int m = 0; m < 4; ++m)
        #pragma unroll
        for (int r = 0; r < 4; ++r) {
            float iv = al[m * 16 + (lane >> 4) * 4 + r];
            int row = q0 + m * 16 + (lane >> 4) * 4 + r;
            #pragma unroll
            for (int n = 0; n < 4; ++n)
                Ao[(size_t)b * N_ * C_ + (size_t)row * C_ + wid * 64 + n * 16 + (lane & 15)] =
                    (bf16)(oac[m][n][r] * iv);
        }
}

// ---------------- kernel 4: out proj + bias + residual ----------------
__global__ __launch_bounds__(256) void k_proj(const bf16* __restrict__ Ao,
                                              const bf16* __restrict__ wo,
                                              const float* __restrict__ ob,
                                              const bf16* __restrict__ xn,
                                              float* __restrict__ out) {
    __shared__ bf16 aT[128 * 64];
    __shared__ bf16 bT[128 * 64];
    int nt = blockIdx.x, ot = blockIdx.y, b = blockIdx.z;
    int tid = threadIdx.x, wid = tid >> 6, lane = tid & 63;
    int wr = wid >> 1, wc = wid & 1;
    const bf16* Abase = wo + (size_t)ot * 128 * C_;
    const bf16* Bbase = Ao + (size_t)b * N_ * C_ + (size_t)nt * 128 * C_;

    bf16x8 areg[4], breg[4];
    #define LOAD_KT(kt)                                                            \
        for (int j = 0; j < 4; ++j) {                                              \
            int lin = (j * 256 + tid) * 8;                                         \
            int row = lin >> 6, col = lin & 63;                                    \
            areg[j] = *(const bf16x8*)&Abase[(size_t)row * C_ + (kt) * 64 + col];  \
            breg[j] = *(const bf16x8*)&Bbase[(size_t)row * C_ + (kt) * 64 + col];  \
        }

    f32x4 acc[4][4] = {};
    LOAD_KT(0);
    for (int kt = 0; kt < 4; ++kt) {
        for (int j = 0; j < 4; ++j) {
            int lin = (j * 256 + tid) * 8;
            *(bf16x8*)&aT[SWZ7(lin)] = areg[j];
            *(bf16x8*)&bT[SWZ7(lin)] = breg[j];
        }
        __syncthreads();
        if (kt < 3) { LOAD_KT(kt + 1); }
        for (int kk = 0; kk < 2; ++kk) {
            bf16x8 af[4], bfr[4];
            for (int m = 0; m < 4; ++m) {
                int el = (wr * 64 + m * 16 + (lane & 15)) * 64 + kk * 32 + (lane >> 4) * 8;
                af[m] = *(const bf16x8*)&aT[SWZ7(el)];
            }
            for (int n = 0; n < 4; ++n) {
                int el = (wc * 64 + n * 16 + (lane & 15)) * 64 + kk * 32 + (lane >> 4) * 8;
                bfr[n] = *(const bf16x8*)&bT[SWZ7(el)];
            }
            for (int m = 0; m < 4; ++m)
                for (int n = 0; n < 4; ++n)
                    acc[m][n] = __builtin_amdgcn_mfma_f32_16x16x32_bf16(af[m], bfr[n], acc[m][n], 0, 0, 0);
        }
        __syncthreads();
    }
    #undef LOAD_KT

    for (int m = 0; m < 4; ++m) {
        int o0 = ot * 128 + wr * 64 + m * 16 + (lane >> 4) * 4;
        for (int n = 0; n < 4; ++n) {
            int col = nt * 128 + wc * 64 + n * 16 + (lane & 15);
            for (int r = 0; r < 4; ++r) {
                int o = o0 + r;
                float v = acc[m][n][r] + ob[o] + (float)xn[(size_t)b * C_ * N_ + (size_t)o * N_ + col];
                out[(size_t)b * C_ * N_ + (size_t)o * N_ + col] = v;
            }
        }
    }
}

// ---------------- launch ----------------
extern "C" void kernel_launch(void* const* d_in, const int* in_sizes, int n_in,
                              void* d_out, int out_size, void* d_ws, size_t ws_size,
                              hipStream_t stream) {
    const float* x     = (const float*)d_in[0];
    const float* gn_w  = (const float*)d_in[1];
    const float* gn_b  = (const float*)d_in[2];
    const float* qkv_w = (const float*)d_in[3];
    const float* qkv_b = (const float*)d_in[4];
    const float* out_w = (const float*)d_in[5];
    const float* out_b = (const float*)d_in[6];
    float* out = (float*)d_out;

    char* ws = (char*)d_ws;
    size_t tensor = (size_t)B_ * C_ * N_ * 2;   // 16.78 MB
    bf16* xn  = (bf16*)(ws);
    bf16* xt  = (bf16*)(ws + tensor);
    bf16* Qs  = (bf16*)(ws + 2 * tensor);
    bf16* Kt  = (bf16*)(ws + 3 * tensor);
    bf16* Vt  = (bf16*)(ws + 4 * tensor);
    bf16* Ao  = xt;                              // alias: xt dead after k_qkv
    bf16* qkv_wh = (bf16*)(ws + 5 * tensor);
    bf16* out_wh = (bf16*)(ws + 5 * tensor + (size_t)O3_ * C_ * 2);

    (void)hipFuncSetAttribute(reinterpret_cast<const void*>(&k_gnconv),
                              hipFuncAttributeMaxDynamicSharedMemorySize, 151552);
    (void)hipFuncSetAttribute(reinterpret_cast<const void*>(&k_attn),
                              hipFuncAttributeMaxDynamicSharedMemorySize, 70912);

    k_gnconv<<<1024, 256, 151552, stream>>>(x, gn_w, gn_b, xn, xt,
                                            qkv_w, out_w, qkv_wh, out_wh);
    k_qkv<<<dim3(8, 6, 32), 256, 0, stream>>>(xt, qkv_wh, qkv_b, Qs, Kt, Vt);
    k_attn<<<dim3(32, 16), 256, 70912, stream>>>(Qs, Kt, Vt, Ao);
    k_proj<<<dim3(8, 2, 32), 256, 0, stream>>>(Ao, out_wh, out_b, xn, out);
}

// Round 13
// 112.330 us; speedup vs baseline: 1.2078x; 1.0452x over previous
//
#include <hip/hip_runtime.h>
#include <hip/hip_bf16.h>

typedef __bf16 bf16;
typedef __bf16 bf16x4 __attribute__((ext_vector_type(4)));
typedef __bf16 bf16x8 __attribute__((ext_vector_type(8)));
typedef float f32x4 __attribute__((ext_vector_type(4)));

#define B_  32
#define C_  256
#define N_  1024
#define G_  8
#define CG_ 32
#define O3_ 768

// LDS XOR swizzles (element-index form). 8-element (16B) chunks preserved.
// 512B rows (256 bf16/row): slot(5b) ^= row&15
#define SWZ9(el) ((el) ^ ((((el) >> 8) & 15) << 3))
// 128B rows (64 bf16/row): slot(3b) ^= row&7
#define SWZ7(el) ((el) ^ ((((el) >> 6) & 7) << 3))

// async global->LDS, 16B per lane. LDS dest must be wave-uniform base (lanes
// auto-scatter base + lane*16); global src is per-lane.
#define GLOAD16(gp, lp)                                                        \
    __builtin_amdgcn_global_load_lds(                                          \
        (const __attribute__((address_space(1))) void*)(gp),                   \
        (__attribute__((address_space(3))) void*)(lp), 16, 0, 0)

// ---------------- kernel 1: group norm (LDS-staged single-pass) + weight convert ----------------
__global__ __launch_bounds__(256) void k_gnconv(const float* __restrict__ x,
                                                const float* __restrict__ w,
                                                const float* __restrict__ bia,
                                                bf16* __restrict__ xn,
                                                bf16* __restrict__ xt,
                                                const float* __restrict__ qkv_w,
                                                const float* __restrict__ out_w,
                                                bf16* __restrict__ qkv_wh,
                                                bf16* __restrict__ out_wh) {
    int blk = blockIdx.x;
    int tid = threadIdx.x;
    if (blk >= 256) {
        int i = (blk - 256) * 256 + tid;
        if (i < O3_ * C_) qkv_wh[i] = (bf16)qkv_w[i];
        if (i < C_ * C_)  out_wh[i] = (bf16)out_w[i];
        return;
    }

    extern __shared__ char smem[];
    float4* xs4 = (float4*)smem;                // 32768 f32 = 128KB
    bf16* tile  = (bf16*)(smem + 131072);       // [256][40] bf16 = 20KB
    int b = blk >> 3, g = blk & 7;
    const float4* xb4 = (const float4*)(x + (size_t)b * C_ * N_ + (size_t)g * CG_ * N_);

    float s = 0.f, ss = 0.f;
    for (int i = tid; i < CG_ * N_ / 4; i += 256) {
        float4 v = xb4[i];
        xs4[i] = v;
        s  += v.x + v.y + v.z + v.w;
        ss += v.x * v.x + v.y * v.y + v.z * v.z + v.w * v.w;
    }
    for (int off = 32; off; off >>= 1) {
        s  += __shfl_down(s, off);
        ss += __shfl_down(ss, off);
    }
    __shared__ float red[8];
    __shared__ float stat[2];
    int wid = tid >> 6, lane = tid & 63;
    if (lane == 0) { red[wid] = s; red[wid + 4] = ss; }
    __syncthreads();
    if (tid == 0) {
        float S  = red[0] + red[1] + red[2] + red[3];
        float SS = red[4] + red[5] + red[6] + red[7];
        float mu = S / (float)(CG_ * N_);
        float var = SS / (float)(CG_ * N_) - mu * mu;
        stat[0] = mu;
        stat[1] = rsqrtf(var + 1e-5f);
    }
    __syncthreads();
    float mu = stat[0], rstd = stat[1];

    for (int nc = 0; nc < N_; nc += 256) {
        for (int i = tid; i < 2048; i += 256) {
            int cl = i >> 6, f = i & 63;
            int c = g * CG_ + cl;
            float sc = rstd * w[c], sh = bia[c] - mu * sc;
            float4 v = xs4[cl * 256 + (nc >> 2) + f];
            bf16x4 h = { (bf16)(v.x * sc + sh), (bf16)(v.y * sc + sh),
                         (bf16)(v.z * sc + sh), (bf16)(v.w * sc + sh) };
            *(bf16x4*)(xn + (size_t)b * C_ * N_ + (size_t)c * N_ + nc + f * 4) = h;
            tile[(f * 4 + 0) * 40 + cl] = h[0];
            tile[(f * 4 + 1) * 40 + cl] = h[1];
            tile[(f * 4 + 2) * 40 + cl] = h[2];
            tile[(f * 4 + 3) * 40 + cl] = h[3];
        }
        __syncthreads();
        for (int u = tid; u < 256 * 4; u += 256) {
            int nl = u >> 2, ch = u & 3;
            bf16x8 v = *(const bf16x8*)&tile[nl * 40 + ch * 8];
            *(bf16x8*)(xt + (size_t)b * N_ * C_ + (size_t)(nc + nl) * C_ + g * CG_ + ch * 8) = v;
        }
        __syncthreads();
    }
}

// ---------------- kernel 2: QKV GEMM ----------------
// Q outputs (ot<2) are pre-scaled by 1/sqrt(C)=1/16 (exact pow2, bit-exact).
__global__ __launch_bounds__(256) void k_qkv(const bf16* __restrict__ xt,
                                             const bf16* __restrict__ wq,
                                             const float* __restrict__ qb,
                                             bf16* __restrict__ Qs,
                                             bf16* __restrict__ Kt,
                                             bf16* __restrict__ Vt) {
    __shared__ bf16 smem[17408];
    bf16* aT = smem;                      // [128][64], swizzled
    bf16* bT = smem + 8192;               // [128][64], swizzled
    int nt = blockIdx.x, ot = blockIdx.y, b = blockIdx.z;
    int tid = threadIdx.x, wid = tid >> 6, lane = tid & 63;
    int wr = wid >> 1, wc = wid & 1;
    const bf16* Ab = xt + (size_t)b * N_ * C_ + (size_t)nt * 128 * C_;
    const bf16* Bb = wq + (size_t)ot * 128 * C_;

    bf16x8 areg[4], breg[4];
    #define LOAD_KT(kt)                                                        \
        for (int j = 0; j < 4; ++j) {                                          \
            int lin = (j * 256 + tid) * 8;                                     \
            int row = lin >> 6, col = lin & 63;                                \
            areg[j] = *(const bf16x8*)&Ab[(size_t)row * C_ + (kt) * 64 + col]; \
            breg[j] = *(const bf16x8*)&Bb[(size_t)row * C_ + (kt) * 64 + col]; \
        }

    f32x4 acc[4][4] = {};
    LOAD_KT(0);
    for (int kt = 0; kt < 4; ++kt) {
        for (int j = 0; j < 4; ++j) {
            int lin = (j * 256 + tid) * 8;
            *(bf16x8*)&aT[SWZ7(lin)] = areg[j];
            *(bf16x8*)&bT[SWZ7(lin)] = breg[j];
        }
        __syncthreads();
        if (kt < 3) { LOAD_KT(kt + 1); }
        for (int kk = 0; kk < 2; ++kk) {
            bf16x8 af[4], bfr[4];
            for (int m = 0; m < 4; ++m) {
                int el = (wr * 64 + m * 16 + (lane & 15)) * 64 + kk * 32 + (lane >> 4) * 8;
                af[m] = *(const bf16x8*)&aT[SWZ7(el)];
            }
            for (int n = 0; n < 4; ++n) {
                int el = (wc * 64 + n * 16 + (lane & 15)) * 64 + kk * 32 + (lane >> 4) * 8;
                bfr[n] = *(const bf16x8*)&bT[SWZ7(el)];
            }
            for (int m = 0; m < 4; ++m)
                for (int n = 0; n < 4; ++n)
                    acc[m][n] = __builtin_amdgcn_mfma_f32_16x16x32_bf16(af[m], bfr[n], acc[m][n], 0, 0, 0);
        }
        __syncthreads();
    }
    #undef LOAD_KT

    int o0 = ot * 128;
    if (ot < 4) {
        bf16* dst = (ot < 2) ? (Qs + (size_t)b * N_ * C_) : (Kt + (size_t)b * N_ * C_);
        float qsc = (ot < 2) ? 0.0625f : 1.0f;
        for (int m = 0; m < 4; ++m) for (int n = 0; n < 4; ++n) {
            int o = o0 + wc * 64 + n * 16 + (lane & 15);
            float bias = qb[o];
            int row0 = nt * 128 + wr * 64 + m * 16 + (lane >> 4) * 4;
            for (int r = 0; r < 4; ++r)
                dst[(size_t)(row0 + r) * C_ + (o & 255)] = (bf16)((acc[m][n][r] + bias) * qsc);
        }
    } else {
        bf16* tileE = smem;               // [128][136]
        for (int m = 0; m < 4; ++m) for (int n = 0; n < 4; ++n) {
            int ol = wc * 64 + n * 16 + (lane & 15);
            float bias = qb[o0 + ol];
            int rl0 = wr * 64 + m * 16 + (lane >> 4) * 4;
            for (int r = 0; r < 4; ++r)
                tileE[(size_t)ol * 136 + rl0 + r] = (bf16)(acc[m][n][r] + bias);
        }
        __syncthreads();
        bf16* Vb = Vt + (size_t)b * C_ * N_ + (size_t)(o0 - 512) * N_ + (size_t)nt * 128;
        for (int u = tid; u < 128 * 16; u += 256) {
            int ol = u >> 4, ch = u & 15;
            bf16x8 v = *(const bf16x8*)&tileE[ol * 136 + ch * 8];
            *(bf16x8*)&Vb[(size_t)ol * N_ + ch * 8] = v;
        }
    }
}

// ---------------- kernel 3: fused attention + out-proj + residual ----------------
// Main loop = R12's v9 (no-max softmax, deferred sums, channel-split PV,
// KVBLK=32, 2 blocks/CU). Epilogue: O (normalized, bf16) -> LDS [64][260]
// (reuses dead kbuf region), one barrier, then per wave a [64o x 64n] GEMM:
// A = out_w rows read DIRECTLY from global (128KB, identical across blocks ->
// L2-hot), B = O tile from LDS; + out_b + xn residual -> out f32. Eliminates
// the Ao round-trip (33MB) and the separate k_proj launch.
__global__ __launch_bounds__(256, 2) void k_attn(const bf16* __restrict__ Qs,
                                                 const bf16* __restrict__ Kt,
                                                 const bf16* __restrict__ Vt,
                                                 const bf16* __restrict__ wo,
                                                 const float* __restrict__ ob,
                                                 const bf16* __restrict__ xn,
                                                 float* __restrict__ out) {
    extern __shared__ char smem[];
    bf16*  kbuf = (bf16*)smem;                  // 2 x 8192 el (32KB)
    bf16*  vbuf = (bf16*)(smem + 32768);        // 2 x 8192 el (32KB)
    bf16*  pl   = (bf16*)(smem + 65536);        // 64 x 40 el = 5120 B
    float* al   = (float*)(smem + 70656);       // 64 floats (1/l, epilogue)
    bf16*  Osm  = (bf16*)smem;                  // epilogue: [64][260] bf16 (33KB, reuses kbuf/vbuf)
    int b = blockIdx.x, qb = blockIdx.y;
    int tid = threadIdx.x, wid = tid >> 6, lane = tid & 63;
    const bf16* Qb = Qs + (size_t)b * N_ * C_;
    const bf16* Kb = Kt + (size_t)b * N_ * C_;
    const bf16* Vb = Vt + (size_t)b * C_ * N_;
    int q0 = qb * 64;

    bf16x8 qf[8];
    {
        int row = q0 + wid * 16 + (lane & 15);
        const bf16* qr = Qb + (size_t)row * C_ + (lane >> 4) * 8;
        #pragma unroll
        for (int kk = 0; kk < 8; ++kk) qf[kk] = *(const bf16x8*)(qr + kk * 32);
    }

    f32x4 oac[4][4] = {};      // O[64q x 64ch]: row m*16+(lane>>4)*4+r, ch wid*64+n*16+(lane&15)
    float lrun[4] = {0.f, 0.f, 0.f, 0.f};   // per-lane partial row sums

    auto stage = [&](int mt, int bi) {
        int m0 = mt * 32;
        bf16* kd = kbuf + bi * 8192;
        bf16* vd = vbuf + bi * 8192;
        #pragma unroll
        for (int j = 0; j < 4; ++j) {
            int chunk = wid * 4 + j;
            int d = chunk * 512 + lane * 8;
            int ek = SWZ9(d);
            int krow = ek >> 8, kcol = ek & 255;
            GLOAD16(Kb + (size_t)(m0 + krow) * C_ + kcol, kd + chunk * 512);
            int ev = SWZ7(d);
            int kv = ev & 31;
            int ch = ((ev >> 6) << 1) | ((ev >> 5) & 1);
            GLOAD16(Vb + (size_t)ch * N_ + m0 + kv, vd + chunk * 512);
        }
    };

    stage(0, 0);
    __syncthreads();

    for (int mt = 0; mt < 32; ++mt) {
        int cur = mt & 1;
        if (mt < 31) stage(mt + 1, cur ^ 1);

        const bf16* kc = kbuf + cur * 8192;
        const bf16* vc = vbuf + cur * 8192;

        // QK^T: S[16q x 32kv]  (Q pre-scaled by 1/16)
        f32x4 sac[2] = {};
        __builtin_amdgcn_s_setprio(1);
        #pragma unroll
        for (int kk = 0; kk < 8; ++kk)
            #pragma unroll
            for (int n = 0; n < 2; ++n) {
                int el = (n * 16 + (lane & 15)) * 256 + kk * 32 + (lane >> 4) * 8;
                bf16x8 bfr = *(const bf16x8*)&kc[SWZ9(el)];
                sac[n] = __builtin_amdgcn_mfma_f32_16x16x32_bf16(qf[kk], bfr, sac[n], 0, 0, 0);
            }
        __builtin_amdgcn_s_setprio(0);

        // exp (no max subtraction; clamp is overflow guard only)
        #pragma unroll
        for (int r = 0; r < 4; ++r) {
            int prow = (wid * 16 + (lane >> 4) * 4 + r) * 40 + (lane & 15);
            float e0 = __expf(fminf(sac[0][r], 60.f));
            float e1 = __expf(fminf(sac[1][r], 60.f));
            lrun[r] += e0 + e1;
            pl[prow]      = (bf16)e0;
            pl[prow + 16] = (bf16)e1;
        }
        __syncthreads();   // P visible block-wide

        // PV channel-split: O[64q x 64ch] += P[64q x 32kv] * V[32kv x 64ch]
        __builtin_amdgcn_s_setprio(1);
        bf16x8 paf[4];
        #pragma unroll
        for (int m = 0; m < 4; ++m)
            paf[m] = *(const bf16x8*)&pl[(m * 16 + (lane & 15)) * 40 + (lane >> 4) * 8];
        #pragma unroll
        for (int n = 0; n < 4; ++n) {
            int ch = wid * 64 + n * 16 + (lane & 15);
            int e = (ch >> 1) * 64 + (ch & 1) * 32 + (lane >> 4) * 8;
            bf16x8 bfr = *(const bf16x8*)&vc[SWZ7(e)];
            #pragma unroll
            for (int m = 0; m < 4; ++m)
                oac[m][n] = __builtin_amdgcn_mfma_f32_16x16x32_bf16(paf[m], bfr, oac[m][n], 0, 0, 0);
        }
        __builtin_amdgcn_s_setprio(0);

        __syncthreads();   // PV reads done; drains t+1 loads; frees P buffer
    }

    // ---- epilogue part 1: row sums -> 1/l ----
    #pragma unroll
    for (int r = 0; r < 4; ++r) {
        float s = lrun[r];
        s += __shfl_xor(s, 1);
        s += __shfl_xor(s, 2);
        s += __shfl_xor(s, 4);
        s += __shfl_xor(s, 8);
        lrun[r] = s;
    }
    if (!(lane & 15)) {
        #pragma unroll
        for (int r = 0; r < 4; ++r)
            al[wid * 16 + (lane >> 4) * 4 + r] = 1.f / lrun[r];
    }
    __syncthreads();

    // ---- epilogue part 2: normalized O -> LDS tile [64 q][260] bf16 ----
    #pragma unroll
    for (int m = 0; m < 4; ++m)
        #pragma unroll
        for (int r = 0; r < 4; ++r) {
            float iv = al[m * 16 + (lane >> 4) * 4 + r];
            int row = m * 16 + (lane >> 4) * 4 + r;
            #pragma unroll
            for (int n = 0; n < 4; ++n)
                Osm[row * 260 + wid * 64 + n * 16 + (lane & 15)] = (bf16)(oac[m][n][r] * iv);
        }
    __syncthreads();

    // ---- epilogue part 3: out-proj GEMM + bias + residual ----
    // wave computes out[64o-slice x 64n]: A = wo rows (global, L2-hot), B = Osm
    {
        f32x4 acc[4][4] = {};
        const bf16* wob = wo + (size_t)wid * 64 * C_;
        #pragma unroll
        for (int kk = 0; kk < 8; ++kk) {
            bf16x8 af[4], bfr[4];
            #pragma unroll
            for (int m = 0; m < 4; ++m)
                af[m] = *(const bf16x8*)&wob[(size_t)(m * 16 + (lane & 15)) * C_ + kk * 32 + (lane >> 4) * 8];
            #pragma unroll
            for (int n = 0; n < 4; ++n)
                bfr[n] = *(const bf16x8*)&Osm[(n * 16 + (lane & 15)) * 260 + kk * 32 + (lane >> 4) * 8];
            #pragma unroll
            for (int m = 0; m < 4; ++m)
                #pragma unroll
                for (int n = 0; n < 4; ++n)
                    acc[m][n] = __builtin_amdgcn_mfma_f32_16x16x32_bf16(af[m], bfr[n], acc[m][n], 0, 0, 0);
        }
        #pragma unroll
        for (int m = 0; m < 4; ++m) {
            int o0 = wid * 64 + m * 16 + (lane >> 4) * 4;
            #pragma unroll
            for (int r = 0; r < 4; ++r) {
                int o = o0 + r;
                float bias = ob[o];
                const bf16* xr = xn + (size_t)b * C_ * N_ + (size_t)o * N_ + q0;
                float* orow = out + (size_t)b * C_ * N_ + (size_t)o * N_ + q0;
                #pragma unroll
                for (int n = 0; n < 4; ++n) {
                    int col = n * 16 + (lane & 15);
                    orow[col] = acc[m][n][r] + bias + (float)xr[col];
                }
            }
        }
    }
}

// ---------------- launch ----------------
extern "C" void kernel_launch(void* const* d_in, const int* in_sizes, int n_in,
                              void* d_out, int out_size, void* d_ws, size_t ws_size,
                              hipStream_t stream) {
    const float* x     = (const float*)d_in[0];
    const float* gn_w  = (const float*)d_in[1];
    const float* gn_b  = (const float*)d_in[2];
    const float* qkv_w = (const float*)d_in[3];
    const float* qkv_b = (const float*)d_in[4];
    const float* out_w = (const float*)d_in[5];
    const float* out_b = (const float*)d_in[6];
    float* out = (float*)d_out;

    char* ws = (char*)d_ws;
    size_t tensor = (size_t)B_ * C_ * N_ * 2;   // 16.78 MB
    bf16* xn  = (bf16*)(ws);
    bf16* xt  = (bf16*)(ws + tensor);
    bf16* Qs  = (bf16*)(ws + 2 * tensor);
    bf16* Kt  = (bf16*)(ws + 3 * tensor);
    bf16* Vt  = (bf16*)(ws + 4 * tensor);
    bf16* qkv_wh = (bf16*)(ws + 5 * tensor);
    bf16* out_wh = (bf16*)(ws + 5 * tensor + (size_t)O3_ * C_ * 2);

    (void)hipFuncSetAttribute(reinterpret_cast<const void*>(&k_gnconv),
                              hipFuncAttributeMaxDynamicSharedMemorySize, 151552);
    (void)hipFuncSetAttribute(reinterpret_cast<const void*>(&k_attn),
                              hipFuncAttributeMaxDynamicSharedMemorySize, 70912);

    k_gnconv<<<1024, 256, 151552, stream>>>(x, gn_w, gn_b, xn, xt,
                                            qkv_w, out_w, qkv_wh, out_wh);
    k_qkv<<<dim3(8, 6, 32), 256, 0, stream>>>(xt, qkv_wh, qkv_b, Qs, Kt, Vt);
    k_attn<<<dim3(32, 16), 256, 70912, stream>>>(Qs, Kt, Vt, out_wh, out_b, xn, out);
}

// Round 14
// 111.777 us; speedup vs baseline: 1.2138x; 1.0050x over previous
//
#include <hip/hip_runtime.h>
#include <hip/hip_bf16.h>

typedef __bf16 bf16;
typedef __bf16 bf16x4 __attribute__((ext_vector_type(4)));
typedef __bf16 bf16x8 __attribute__((ext_vector_type(8)));
typedef float f32x4 __attribute__((ext_vector_type(4)));

#define B_  32
#define C_  256
#define N_  1024
#define G_  8
#define CG_ 32
#define O3_ 768

// LDS XOR swizzles (element-index form). 8-element (16B) chunks preserved.
// 512B rows (256 bf16/row): slot(5b) ^= row&15
#define SWZ9(el) ((el) ^ ((((el) >> 8) & 15) << 3))
// 128B rows (64 bf16/row): slot(3b) ^= row&7
#define SWZ7(el) ((el) ^ ((((el) >> 6) & 7) << 3))

// async global->LDS, 16B per lane. LDS dest must be wave-uniform base (lanes
// auto-scatter base + lane*16); global src is per-lane.
#define GLOAD16(gp, lp)                                                        \
    __builtin_amdgcn_global_load_lds(                                          \
        (const __attribute__((address_space(1))) void*)(gp),                   \
        (__attribute__((address_space(3))) void*)(lp), 16, 0, 0)

// ---------------- kernel 1: group norm (LDS-staged single-pass) + weight convert ----------------
__global__ __launch_bounds__(256) void k_gnconv(const float* __restrict__ x,
                                                const float* __restrict__ w,
                                                const float* __restrict__ bia,
                                                bf16* __restrict__ xn,
                                                bf16* __restrict__ xt,
                                                const float* __restrict__ qkv_w,
                                                const float* __restrict__ out_w,
                                                bf16* __restrict__ qkv_wh,
                                                bf16* __restrict__ out_wh) {
    int blk = blockIdx.x;
    int tid = threadIdx.x;
    if (blk >= 256) {
        int i = (blk - 256) * 256 + tid;
        if (i < O3_ * C_) qkv_wh[i] = (bf16)qkv_w[i];
        if (i < C_ * C_)  out_wh[i] = (bf16)out_w[i];
        return;
    }

    extern __shared__ char smem[];
    float4* xs4 = (float4*)smem;                // 32768 f32 = 128KB
    bf16* tile  = (bf16*)(smem + 131072);       // [256][40] bf16 = 20KB
    int b = blk >> 3, g = blk & 7;
    const float4* xb4 = (const float4*)(x + (size_t)b * C_ * N_ + (size_t)g * CG_ * N_);

    float s = 0.f, ss = 0.f;
    for (int i = tid; i < CG_ * N_ / 4; i += 256) {
        float4 v = xb4[i];
        xs4[i] = v;
        s  += v.x + v.y + v.z + v.w;
        ss += v.x * v.x + v.y * v.y + v.z * v.z + v.w * v.w;
    }
    for (int off = 32; off; off >>= 1) {
        s  += __shfl_down(s, off);
        ss += __shfl_down(ss, off);
    }
    __shared__ float red[8];
    __shared__ float stat[2];
    int wid = tid >> 6, lane = tid & 63;
    if (lane == 0) { red[wid] = s; red[wid + 4] = ss; }
    __syncthreads();
    if (tid == 0) {
        float S  = red[0] + red[1] + red[2] + red[3];
        float SS = red[4] + red[5] + red[6] + red[7];
        float mu = S / (float)(CG_ * N_);
        float var = SS / (float)(CG_ * N_) - mu * mu;
        stat[0] = mu;
        stat[1] = rsqrtf(var + 1e-5f);
    }
    __syncthreads();
    float mu = stat[0], rstd = stat[1];

    for (int nc = 0; nc < N_; nc += 256) {
        for (int i = tid; i < 2048; i += 256) {
            int cl = i >> 6, f = i & 63;
            int c = g * CG_ + cl;
            float sc = rstd * w[c], sh = bia[c] - mu * sc;
            float4 v = xs4[cl * 256 + (nc >> 2) + f];
            bf16x4 h = { (bf16)(v.x * sc + sh), (bf16)(v.y * sc + sh),
                         (bf16)(v.z * sc + sh), (bf16)(v.w * sc + sh) };
            *(bf16x4*)(xn + (size_t)b * C_ * N_ + (size_t)c * N_ + nc + f * 4) = h;
            tile[(f * 4 + 0) * 40 + cl] = h[0];
            tile[(f * 4 + 1) * 40 + cl] = h[1];
            tile[(f * 4 + 2) * 40 + cl] = h[2];
            tile[(f * 4 + 3) * 40 + cl] = h[3];
        }
        __syncthreads();
        for (int u = tid; u < 256 * 4; u += 256) {
            int nl = u >> 2, ch = u & 3;
            bf16x8 v = *(const bf16x8*)&tile[nl * 40 + ch * 8];
            *(bf16x8*)(xt + (size_t)b * N_ * C_ + (size_t)(nc + nl) * C_ + g * CG_ + ch * 8) = v;
        }
        __syncthreads();
    }
}

// ---------------- kernel 2: QKV GEMM ----------------
// Q outputs (ot<2) pre-scaled by log2(e)/sqrt(C) = 0.0625*1.4427 so attention
// can use native 2^x (v_exp_f32) with no per-element multiply.
__global__ __launch_bounds__(256) void k_qkv(const bf16* __restrict__ xt,
                                             const bf16* __restrict__ wq,
                                             const float* __restrict__ qb,
                                             bf16* __restrict__ Qs,
                                             bf16* __restrict__ Kt,
                                             bf16* __restrict__ Vt) {
    __shared__ bf16 smem[17408];
    bf16* aT = smem;                      // [128][64], swizzled
    bf16* bT = smem + 8192;               // [128][64], swizzled
    int nt = blockIdx.x, ot = blockIdx.y, b = blockIdx.z;
    int tid = threadIdx.x, wid = tid >> 6, lane = tid & 63;
    int wr = wid >> 1, wc = wid & 1;
    const bf16* Ab = xt + (size_t)b * N_ * C_ + (size_t)nt * 128 * C_;
    const bf16* Bb = wq + (size_t)ot * 128 * C_;

    bf16x8 areg[4], breg[4];
    #define LOAD_KT(kt)                                                        \
        for (int j = 0; j < 4; ++j) {                                          \
            int lin = (j * 256 + tid) * 8;                                     \
            int row = lin >> 6, col = lin & 63;                                \
            areg[j] = *(const bf16x8*)&Ab[(size_t)row * C_ + (kt) * 64 + col]; \
            breg[j] = *(const bf16x8*)&Bb[(size_t)row * C_ + (kt) * 64 + col]; \
        }

    f32x4 acc[4][4] = {};
    LOAD_KT(0);
    for (int kt = 0; kt < 4; ++kt) {
        for (int j = 0; j < 4; ++j) {
            int lin = (j * 256 + tid) * 8;
            *(bf16x8*)&aT[SWZ7(lin)] = areg[j];
            *(bf16x8*)&bT[SWZ7(lin)] = breg[j];
        }
        __syncthreads();
        if (kt < 3) { LOAD_KT(kt + 1); }
        for (int kk = 0; kk < 2; ++kk) {
            bf16x8 af[4], bfr[4];
            for (int m = 0; m < 4; ++m) {
                int el = (wr * 64 + m * 16 + (lane & 15)) * 64 + kk * 32 + (lane >> 4) * 8;
                af[m] = *(const bf16x8*)&aT[SWZ7(el)];
            }
            for (int n = 0; n < 4; ++n) {
                int el = (wc * 64 + n * 16 + (lane & 15)) * 64 + kk * 32 + (lane >> 4) * 8;
                bfr[n] = *(const bf16x8*)&bT[SWZ7(el)];
            }
            for (int m = 0; m < 4; ++m)
                for (int n = 0; n < 4; ++n)
                    acc[m][n] = __builtin_amdgcn_mfma_f32_16x16x32_bf16(af[m], bfr[n], acc[m][n], 0, 0, 0);
        }
        __syncthreads();
    }
    #undef LOAD_KT

    int o0 = ot * 128;
    if (ot < 4) {
        bf16* dst = (ot < 2) ? (Qs + (size_t)b * N_ * C_) : (Kt + (size_t)b * N_ * C_);
        float qsc = (ot < 2) ? 0.09016844f : 1.0f;   // log2(e)/16
        for (int m = 0; m < 4; ++m) for (int n = 0; n < 4; ++n) {
            int o = o0 + wc * 64 + n * 16 + (lane & 15);
            float bias = qb[o];
            int row0 = nt * 128 + wr * 64 + m * 16 + (lane >> 4) * 4;
            for (int r = 0; r < 4; ++r)
                dst[(size_t)(row0 + r) * C_ + (o & 255)] = (bf16)((acc[m][n][r] + bias) * qsc);
        }
    } else {
        bf16* tileE = smem;               // [128][136]
        for (int m = 0; m < 4; ++m) for (int n = 0; n < 4; ++n) {
            int ol = wc * 64 + n * 16 + (lane & 15);
            float bias = qb[o0 + ol];
            int rl0 = wr * 64 + m * 16 + (lane >> 4) * 4;
            for (int r = 0; r < 4; ++r)
                tileE[(size_t)ol * 136 + rl0 + r] = (bf16)(acc[m][n][r] + bias);
        }
        __syncthreads();
        bf16* Vb = Vt + (size_t)b * C_ * N_ + (size_t)(o0 - 512) * N_ + (size_t)nt * 128;
        for (int u = tid; u < 128 * 16; u += 256) {
            int ol = u >> 4, ch = u & 15;
            bf16x8 v = *(const bf16x8*)&tileE[ol * 136 + ch * 8];
            *(bf16x8*)&Vb[(size_t)ol * N_ + ch * 8] = v;
        }
    }
}

// ---------------- kernel 3: fused attention + out-proj + residual ----------------
// v9 main loop (no-max softmax via native exp2 — scores arrive pre-scaled by
// log2e/16, so softmax weight = 2^s / sum 2^s == exp-softmax; clamp 86 is the
// 2^86 overflow guard). Deferred per-lane row sums; channel-split PV;
// KVBLK=32; 2 blocks/CU. Epilogue: normalized O -> LDS, out-proj GEMM with
// wo from global (L2-hot) + bias + xn residual -> out f32.
__global__ __launch_bounds__(256, 2) void k_attn(const bf16* __restrict__ Qs,
                                                 const bf16* __restrict__ Kt,
                                                 const bf16* __restrict__ Vt,
                                                 const bf16* __restrict__ wo,
                                                 const float* __restrict__ ob,
                                                 const bf16* __restrict__ xn,
                                                 float* __restrict__ out) {
    extern __shared__ char smem[];
    bf16*  kbuf = (bf16*)smem;                  // 2 x 8192 el (32KB)
    bf16*  vbuf = (bf16*)(smem + 32768);        // 2 x 8192 el (32KB)
    bf16*  pl   = (bf16*)(smem + 65536);        // 64 x 40 el = 5120 B
    float* al   = (float*)(smem + 70656);       // 64 floats (1/l, epilogue)
    bf16*  Osm  = (bf16*)smem;                  // epilogue: [64][260] bf16 (33KB, reuses kbuf/vbuf)
    int b = blockIdx.x, qb = blockIdx.y;
    int tid = threadIdx.x, wid = tid >> 6, lane = tid & 63;
    const bf16* Qb = Qs + (size_t)b * N_ * C_;
    const bf16* Kb = Kt + (size_t)b * N_ * C_;
    const bf16* Vb = Vt + (size_t)b * C_ * N_;
    int q0 = qb * 64;

    bf16x8 qf[8];
    {
        int row = q0 + wid * 16 + (lane & 15);
        const bf16* qr = Qb + (size_t)row * C_ + (lane >> 4) * 8;
        #pragma unroll
        for (int kk = 0; kk < 8; ++kk) qf[kk] = *(const bf16x8*)(qr + kk * 32);
    }

    f32x4 oac[4][4] = {};      // O[64q x 64ch]: row m*16+(lane>>4)*4+r, ch wid*64+n*16+(lane&15)
    float lrun[4] = {0.f, 0.f, 0.f, 0.f};   // per-lane partial row sums

    auto stage = [&](int mt, int bi) {
        int m0 = mt * 32;
        bf16* kd = kbuf + bi * 8192;
        bf16* vd = vbuf + bi * 8192;
        #pragma unroll
        for (int j = 0; j < 4; ++j) {
            int chunk = wid * 4 + j;
            int d = chunk * 512 + lane * 8;
            int ek = SWZ9(d);
            int krow = ek >> 8, kcol = ek & 255;
            GLOAD16(Kb + (size_t)(m0 + krow) * C_ + kcol, kd + chunk * 512);
            int ev = SWZ7(d);
            int kv = ev & 31;
            int ch = ((ev >> 6) << 1) | ((ev >> 5) & 1);
            GLOAD16(Vb + (size_t)ch * N_ + m0 + kv, vd + chunk * 512);
        }
    };

    stage(0, 0);
    __syncthreads();

    for (int mt = 0; mt < 32; ++mt) {
        int cur = mt & 1;
        if (mt < 31) stage(mt + 1, cur ^ 1);

        const bf16* kc = kbuf + cur * 8192;
        const bf16* vc = vbuf + cur * 8192;

        // QK^T: S[16q x 32kv]  (Q pre-scaled by log2e/16)
        f32x4 sac[2] = {};
        __builtin_amdgcn_s_setprio(1);
        #pragma unroll
        for (int kk = 0; kk < 8; ++kk)
            #pragma unroll
            for (int n = 0; n < 2; ++n) {
                int el = (n * 16 + (lane & 15)) * 256 + kk * 32 + (lane >> 4) * 8;
                bf16x8 bfr = *(const bf16x8*)&kc[SWZ9(el)];
                sac[n] = __builtin_amdgcn_mfma_f32_16x16x32_bf16(qf[kk], bfr, sac[n], 0, 0, 0);
            }
        __builtin_amdgcn_s_setprio(0);

        // softmax numerator via native 2^x (no max subtraction; clamp 86 guard)
        #pragma unroll
        for (int r = 0; r < 4; ++r) {
            int prow = (wid * 16 + (lane >> 4) * 4 + r) * 40 + (lane & 15);
            float e0 = __builtin_amdgcn_exp2f(fminf(sac[0][r], 86.f));
            float e1 = __builtin_amdgcn_exp2f(fminf(sac[1][r], 86.f));
            lrun[r] += e0 + e1;
            pl[prow]      = (bf16)e0;
            pl[prow + 16] = (bf16)e1;
        }
        __syncthreads();   // P visible block-wide

        // PV channel-split: O[64q x 64ch] += P[64q x 32kv] * V[32kv x 64ch]
        __builtin_amdgcn_s_setprio(1);
        bf16x8 paf[4];
        #pragma unroll
        for (int m = 0; m < 4; ++m)
            paf[m] = *(const bf16x8*)&pl[(m * 16 + (lane & 15)) * 40 + (lane >> 4) * 8];
        #pragma unroll
        for (int n = 0; n < 4; ++n) {
            int ch = wid * 64 + n * 16 + (lane & 15);
            int e = (ch >> 1) * 64 + (ch & 1) * 32 + (lane >> 4) * 8;
            bf16x8 bfr = *(const bf16x8*)&vc[SWZ7(e)];
            #pragma unroll
            for (int m = 0; m < 4; ++m)
                oac[m][n] = __builtin_amdgcn_mfma_f32_16x16x32_bf16(paf[m], bfr, oac[m][n], 0, 0, 0);
        }
        __builtin_amdgcn_s_setprio(0);

        __syncthreads();   // PV reads done; drains t+1 loads; frees P buffer
    }

    // ---- epilogue part 1: row sums -> 1/l ----
    #pragma unroll
    for (int r = 0; r < 4; ++r) {
        float s = lrun[r];
        s += __shfl_xor(s, 1);
        s += __shfl_xor(s, 2);
        s += __shfl_xor(s, 4);
        s += __shfl_xor(s, 8);
        lrun[r] = s;
    }
    if (!(lane & 15)) {
        #pragma unroll
        for (int r = 0; r < 4; ++r)
            al[wid * 16 + (lane >> 4) * 4 + r] = 1.f / lrun[r];
    }
    __syncthreads();

    // ---- epilogue part 2: normalized O -> LDS tile [64 q][260] bf16 ----
    #pragma unroll
    for (int m = 0; m < 4; ++m)
        #pragma unroll
        for (int r = 0; r < 4; ++r) {
            float iv = al[m * 16 + (lane >> 4) * 4 + r];
            int row = m * 16 + (lane >> 4) * 4 + r;
            #pragma unroll
            for (int n = 0; n < 4; ++n)
                Osm[row * 260 + wid * 64 + n * 16 + (lane & 15)] = (bf16)(oac[m][n][r] * iv);
        }
    __syncthreads();

    // ---- epilogue part 3: out-proj GEMM + bias + residual ----
    {
        f32x4 acc[4][4] = {};
        const bf16* wob = wo + (size_t)wid * 64 * C_;
        #pragma unroll
        for (int kk = 0; kk < 8; ++kk) {
            bf16x8 af[4], bfr[4];
            #pragma unroll
            for (int m = 0; m < 4; ++m)
                af[m] = *(const bf16x8*)&wob[(size_t)(m * 16 + (lane & 15)) * C_ + kk * 32 + (lane >> 4) * 8];
            #pragma unroll
            for (int n = 0; n < 4; ++n)
                bfr[n] = *(const bf16x8*)&Osm[(n * 16 + (lane & 15)) * 260 + kk * 32 + (lane >> 4) * 8];
            #pragma unroll
            for (int m = 0; m < 4; ++m)
                #pragma unroll
                for (int n = 0; n < 4; ++n)
                    acc[m][n] = __builtin_amdgcn_mfma_f32_16x16x32_bf16(af[m], bfr[n], acc[m][n], 0, 0, 0);
        }
        #pragma unroll
        for (int m = 0; m < 4; ++m) {
            int o0 = wid * 64 + m * 16 + (lane >> 4) * 4;
            #pragma unroll
            for (int r = 0; r < 4; ++r) {
                int o = o0 + r;
                float bias = ob[o];
                const bf16* xr = xn + (size_t)b * C_ * N_ + (size_t)o * N_ + q0;
                float* orow = out + (size_t)b * C_ * N_ + (size_t)o * N_ + q0;
                #pragma unroll
                for (int n = 0; n < 4; ++n) {
                    int col = n * 16 + (lane & 15);
                    orow[col] = acc[m][n][r] + bias + (float)xr[col];
                }
            }
        }
    }
}

// ---------------- launch ----------------
extern "C" void kernel_launch(void* const* d_in, const int* in_sizes, int n_in,
                              void* d_out, int out_size, void* d_ws, size_t ws_size,
                              hipStream_t stream) {
    const float* x     = (const float*)d_in[0];
    const float* gn_w  = (const float*)d_in[1];
    const float* gn_b  = (const float*)d_in[2];
    const float* qkv_w = (const float*)d_in[3];
    const float* qkv_b = (const float*)d_in[4];
    const float* out_w = (const float*)d_in[5];
    const float* out_b = (const float*)d_in[6];
    float* out = (float*)d_out;

    char* ws = (char*)d_ws;
    size_t tensor = (size_t)B_ * C_ * N_ * 2;   // 16.78 MB
    bf16* xn  = (bf16*)(ws);
    bf16* xt  = (bf16*)(ws + tensor);
    bf16* Qs  = (bf16*)(ws + 2 * tensor);
    bf16* Kt  = (bf16*)(ws + 3 * tensor);
    bf16* Vt  = (bf16*)(ws + 4 * tensor);
    bf16* qkv_wh = (bf16*)(ws + 5 * tensor);
    bf16* out_wh = (bf16*)(ws + 5 * tensor + (size_t)O3_ * C_ * 2);

    (void)hipFuncSetAttribute(reinterpret_cast<const void*>(&k_gnconv),
                              hipFuncAttributeMaxDynamicSharedMemorySize, 151552);
    (void)hipFuncSetAttribute(reinterpret_cast<const void*>(&k_attn),
                              hipFuncAttributeMaxDynamicSharedMemorySize, 70912);

    k_gnconv<<<1024, 256, 151552, stream>>>(x, gn_w, gn_b, xn, xt,
                                            qkv_w, out_w, qkv_wh, out_wh);
    k_qkv<<<dim3(8, 6, 32), 256, 0, stream>>>(xt, qkv_wh, qkv_b, Qs, Kt, Vt);
    k_attn<<<dim3(32, 16), 256, 70912, stream>>>(Qs, Kt, Vt, out_wh, out_b, xn, out);
}